// Round 6
// baseline (112.628 us; speedup 1.0000x reference)
//
#include <hip/hip_runtime.h>
#include <hip/hip_bf16.h>
#include <stdint.h>

// Problem constants (SelfAttentionHead): B=8, T=2048, E=1024, D=128
#define Bq 8
#define Tq 2048
#define Eq 1024
#define Dq 128
#define BLOCKS_PER_B 144          // sum_{g=0..31} ceil((g+1)/4), LSEG=256
#define NBLK (Bq * BLOCKS_PER_B)  // 1152

typedef __attribute__((ext_vector_type(8))) short short8;   // 8 x bf16 (4 VGPR) MFMA frag
typedef __attribute__((ext_vector_type(4))) float f32x4;    // MFMA accumulator

__device__ __forceinline__ unsigned short f2b(float f) {
  __hip_bfloat16 h = __float2bfloat16(f);   // RNE
  return __builtin_bit_cast(unsigned short, h);
}
__device__ __forceinline__ float b2f(unsigned short u) {
  unsigned int x = ((unsigned int)u) << 16;
  return __builtin_bit_cast(float, x);
}
__device__ __forceinline__ void gload16(const void* g, void* l) {
  __builtin_amdgcn_global_load_lds(
      (const __attribute__((address_space(1))) unsigned int*)g,
      (__attribute__((address_space(3))) unsigned int*)l, 16, 0, 0);
}

// ------------- weights: transpose + cast via LDS -> wt[p][d][e] = W_p[e][d]; p: 0=Wq 1=Wk 2=Wv -------------
__global__ __launch_bounds__(256) void prep_w_kernel(const float* __restrict__ wq,
                                                     const float* __restrict__ wk,
                                                     const float* __restrict__ wv,
                                                     unsigned short* __restrict__ wt) {
  __shared__ float tile[64][129];
  const int p  = blockIdx.x >> 4;
  const int e0 = (blockIdx.x & 15) * 64;
  const float* w = (p == 0) ? wq : (p == 1) ? wk : wv;
  const int tid = threadIdx.x;
#pragma unroll
  for (int i = 0; i < 32; ++i) {
    int idx = i * 256 + tid;            // 0..8191
    int r = idx >> 7, c = idx & 127;
    tile[r][c] = w[(size_t)(e0 + r) * Dq + c];
  }
  __syncthreads();
  const int d = tid >> 1;
  const int es = (tid & 1) * 32;
  unsigned short* dst = wt + (size_t)p * Dq * Eq + (size_t)d * Eq + e0 + es;
#pragma unroll
  for (int c4 = 0; c4 < 8; ++c4) {
    ushort4 u;
    u.x = f2b(tile[es + c4 * 4 + 0][d]);
    u.y = f2b(tile[es + c4 * 4 + 1][d]);
    u.z = f2b(tile[es + c4 * 4 + 2][d]);
    u.w = f2b(tile[es + c4 * 4 + 3][d]);
    *reinterpret_cast<ushort4*>(dst + c4 * 4) = u;
  }
}

// ------------- fully fused projection GEMM: C[16384 x 384] = x(f32) @ [Wq|Wk|Wv] -------------
// 256 blocks x 512 thr (8 waves, 2x4; wave = 32 rows x 96 cols = 2x6 frags). BK=32, 32 steps.
// x read ONCE from HBM. A: reg-staged f32->bf16 into transposed [kchunk][row] LDS (conflict-free).
// B: global_load_lds w/ both-sides XOR swizzle. 2-phase double-buffer, 1 barrier/step.
__global__ __launch_bounds__(512) void proj3_kernel(const float* __restrict__ x,
                                                    const unsigned short* __restrict__ wt,
                                                    unsigned short* __restrict__ qo,
                                                    unsigned short* __restrict__ ko,
                                                    unsigned short* __restrict__ vo) {
  __shared__ __align__(16) char As[2][4096];    // A: 4 kchunks x 64 rows x 16B (8 bf16)
  __shared__ __align__(16) char Bs[2][24576];   // B: 384 cols x 32 bf16 (64B), XOR-swizzled

  const int row0 = blockIdx.x * 64;
  const int tid  = threadIdx.x;
  const int lane = tid & 63;
  const int w    = tid >> 6;
  const int wm   = w >> 2, wn = w & 3;          // wave = rows [32wm,32wm+32) x cols [96wn,96wn+96)
  const int lrow = lane & 15;
  const int lgrp = lane >> 4;
  const char* wtbyte = (const char*)wt;         // [p][d][e] contiguous: col*2048 indexes all 384

  // A staging: thread -> (row = tid>>3, 16B-of-f32 chunk a16 = tid&7); one float4 (4 f32 -> 4 bf16 = 8B)
  const int arow = tid >> 3;
  const int a16  = tid & 7;
  const float* asrc_base = x + (size_t)(row0 + arow) * Eq + a16 * 4;
  const int awr = (a16 >> 1) * 1024 + arow * 16 + (a16 & 1) * 8;   // transposed dest byte

  auto BSTAGE = [&](int bufi, int ks) {
#pragma unroll
    for (int i = 0; i < 3; ++i) {
      int y  = i * 8192 + w * 1024;             // wave-uniform LDS base
      int yl = y + lane * 16;
      int col = yl >> 6, off = yl & 63;
      gload16(wtbyte + (size_t)col * 2048 + ks * 2 + (off ^ (((col >> 1) & 3) << 4)),
              Bs[bufi] + y);
    }
  };
  auto AWRITE = [&](int bufi, float4 f) {
    ushort4 u;
    u.x = f2b(f.x); u.y = f2b(f.y); u.z = f2b(f.z); u.w = f2b(f.w);
    *reinterpret_cast<ushort4*>(As[bufi] + awr) = u;
  };

  f32x4 acc[2][6];
#pragma unroll
  for (int m = 0; m < 2; ++m)
#pragma unroll
    for (int n = 0; n < 6; ++n) acc[m][n] = (f32x4){0.f, 0.f, 0.f, 0.f};

  // prologue: stage step 0
  {
    float4 f = *reinterpret_cast<const float4*>(asrc_base);
    BSTAGE(0, 0);
    AWRITE(0, f);
  }
  __syncthreads();

  for (int s = 0; s < 32; ++s) {
    const int cur = s & 1;
    float4 nf;
    if (s < 31) {
      nf = *reinterpret_cast<const float4*>(asrc_base + (s + 1) * 32);  // issue early
      BSTAGE(cur ^ 1, (s + 1) * 32);                                    // in flight during compute
    }

    // ---- compute step s from LDS ----
    const char* Ab = As[cur];
    const char* Bb = Bs[cur];
    short8 af[2], bf_[6];
#pragma unroll
    for (int m = 0; m < 2; ++m) {
      int ar = wm * 32 + m * 16 + lrow;
      af[m] = *reinterpret_cast<const short8*>(Ab + lgrp * 1024 + ar * 16);
    }
#pragma unroll
    for (int n = 0; n < 6; ++n) {
      int bc = wn * 96 + n * 16 + lrow;
      bf_[n] = *reinterpret_cast<const short8*>(Bb + bc * 64 + ((lgrp * 16) ^ (((bc >> 1) & 3) << 4)));
    }
#pragma unroll
    for (int m = 0; m < 2; ++m)
#pragma unroll
      for (int n = 0; n < 6; ++n)
        acc[m][n] = __builtin_amdgcn_mfma_f32_16x16x32_bf16(af[m], bf_[n], acc[m][n], 0, 0, 0);

    if (s < 31) AWRITE(cur ^ 1, nf);
    __syncthreads();   // drains B gloads (vmcnt) + A ds_writes (lgkm); all waves done with cur
  }

  // epilogue: C/D layout col=lane&15, row=(lane>>4)*4+reg
  const int rg   = (lane >> 4) * 4;
  const int lcol = lane & 15;
#pragma unroll
  for (int m = 0; m < 2; ++m)
#pragma unroll
    for (int n = 0; n < 6; ++n) {
      int col = wn * 96 + n * 16 + lcol;
      int p = col >> 7, d = col & 127;
#pragma unroll
      for (int r = 0; r < 4; ++r) {
        int row = row0 + wm * 32 + m * 16 + rg + r;
        float v = acc[m][n][r];
        if (p == 0)      qo[(size_t)row * Dq + d] = f2b(v);
        else if (p == 1) ko[(size_t)row * Dq + d] = f2b(v);
        else             vo[(size_t)(row >> 11) * Dq * Tq + (size_t)d * Tq + (row & (Tq - 1))] = f2b(v);
      }
    }
}

// ------------- split-KV causal flash attention, block-cooperative LDS staging -------------
// Block (256 thr = 4 waves) = (batch b, 64-row Q group g, KV segment s of 256).
// Wave w owns rows 64g+16w..+15. Per 64-col step: cooperative K/V tile DMA to LDS
// (double-buffered, source-swizzled), then per-wave QK/softmax/PV from LDS.
__global__ __launch_bounds__(256) void attn_kernel(const unsigned short* __restrict__ q,
                                                   const unsigned short* __restrict__ k,
                                                   const unsigned short* __restrict__ vT,
                                                   unsigned short* __restrict__ pO,
                                                   float* __restrict__ pm,
                                                   float* __restrict__ pl) {
  __shared__ __align__(16) char kbuf[2][16384];            // K tile: 64 rows x 256B
  __shared__ __align__(16) char vbuf[2][16384];            // V tile: 128 d-rows x 128B
  __shared__ __align__(16) unsigned short pbuf[4][1024];   // per-wave P tile 16x64

  const int lane = threadIdx.x & 63;
  const int w    = threadIdx.x >> 6;
  const int bx   = blockIdx.x;
  const int b    = bx / BLOCKS_PER_B;
  int rm = bx - b * BLOCKS_PER_B;
  int g = 0, s = 0;
#pragma unroll
  for (int c = 1; c <= 8; ++c) {        // groups 4(c-1)..4c-1 have c segments each
    int cnt = 4 * c;
    if (rm < cnt) { g = 4 * (c - 1) + rm / c; s = rm % c; break; }
    rm -= cnt;
  }
  const int kv0      = 256 * s;
  const int kend_blk = min(kv0 + 256, 64 * g + 64);
  const int qb0      = 64 * g + 16 * w;
  const int kend_w   = qb0 + 16;

  const int lrow = lane & 15;
  const int lgrp = lane >> 4;
  const int lk8  = lgrp * 8;
  const float kscale = 0.08838834764831845f * 1.44269504088896340736f; // D^-0.5 * log2(e)
  unsigned short* pb = pbuf[w];
  const char* kgbase = (const char*)(k + (size_t)b * Tq * Dq);
  const char* vgbase = (const char*)(vT + (size_t)b * Dq * Tq);

  // cooperative stage of one 64-col K/V tile pair into buffer `bufi`
  auto STAGE = [&](int bufi, int kvb) {
    const char* ksrc = kgbase + (size_t)kvb * 256;   // contiguous 16KB
    char* kl = kbuf[bufi];
    char* vl = vbuf[bufi];
    const int kvb2 = kvb * 2;
#pragma unroll
    for (int i = 0; i < 4; ++i) {
      int y  = i * 4096 + w * 1024;                  // wave-uniform LDS byte base
      int yl = y + lane * 16;                        // this lane's dest byte
      int src = yl ^ ((((yl >> 8) & 7)) << 4);       // inverse swizzle on source
      gload16(ksrc + src, kl + y);
    }
#pragma unroll
    for (int i = 0; i < 4; ++i) {
      int y  = i * 4096 + w * 1024;
      int yl = y + lane * 16;
      int d  = yl >> 7;
      int src = d * 4096 + kvb2 + ((yl & 127) ^ ((d & 7) << 4));
      gload16(vgbase + src, vl + y);
    }
  };

  // Q fragments (registers)
  short8 qf[4];
  const unsigned short* qrow = q + ((size_t)b * Tq + qb0 + lrow) * Dq;
#pragma unroll
  for (int kc = 0; kc < 4; ++kc)
    qf[kc] = *reinterpret_cast<const short8*>(qrow + kc * 32 + lk8);

  f32x4 o[8];
#pragma unroll
  for (int n = 0; n < 8; ++n) o[n] = (f32x4){0.f, 0.f, 0.f, 0.f};
  float m[4], l[4];
#pragma unroll
  for (int r = 0; r < 4; ++r) { m[r] = -1e30f; l[r] = 0.f; }
  const int rowg = qb0 + lgrp * 4;

  STAGE(0, kv0);
  const int nsteps = (kend_blk - kv0) >> 6;
  __syncthreads();                                   // buf0 ready (vmcnt(0)+barrier)

  for (int t = 0; t < nsteps; ++t) {
    const int kvb = kv0 + (t << 6);
    const int cur = t & 1;
    if (t + 1 < nsteps) STAGE(cur ^ 1, kvb + 64);    // prefetch next tile (in flight during compute)

    if (kvb < kend_w) {
      const char* kbp = kbuf[cur];
      // ---- QK^T: 64 score cols from LDS ----
      f32x4 sf[4];
#pragma unroll
      for (int n = 0; n < 4; ++n) sf[n] = (f32x4){0.f, 0.f, 0.f, 0.f};
#pragma unroll
      for (int kc = 0; kc < 4; ++kc)
#pragma unroll
        for (int n = 0; n < 4; ++n) {
          int u = (n * 16 + lrow) * 256 + kc * 64 + lgrp * 16;
          short8 kf = *reinterpret_cast<const short8*>(kbp + (u ^ ((lrow & 7) << 4)));
          sf[n] = __builtin_amdgcn_mfma_f32_16x16x32_bf16(qf[kc], kf, sf[n], 0, 0, 0);
        }

      // ---- scale + causal mask + online softmax ----
      const bool needmask = (kvb + 64 > qb0);
      float p[4][4], mx[4];
#pragma unroll
      for (int r = 0; r < 4; ++r) mx[r] = -1e30f;
#pragma unroll
      for (int n = 0; n < 4; ++n)
#pragma unroll
        for (int r = 0; r < 4; ++r) {
          float aa = sf[n][r] * kscale;
          if (needmask && (kvb + n * 16 + lrow > rowg + r)) aa = -1e30f;
          p[n][r] = aa;
          mx[r] = fmaxf(mx[r], aa);
        }
#pragma unroll
      for (int off = 1; off < 16; off <<= 1)
#pragma unroll
        for (int r = 0; r < 4; ++r) mx[r] = fmaxf(mx[r], __shfl_xor(mx[r], off, 64));

      float alpha[4], sm[4];
#pragma unroll
      for (int r = 0; r < 4; ++r) {
        float mn = fmaxf(m[r], mx[r]);
        alpha[r] = exp2f(m[r] - mn);
        m[r] = mn;
        sm[r] = 0.f;
#pragma unroll
        for (int n = 0; n < 4; ++n) {
          p[n][r] = exp2f(p[n][r] - mn);
          sm[r] += p[n][r];
        }
      }
#pragma unroll
      for (int off = 1; off < 16; off <<= 1)
#pragma unroll
        for (int r = 0; r < 4; ++r) sm[r] += __shfl_xor(sm[r], off, 64);
#pragma unroll
      for (int r = 0; r < 4; ++r) l[r] = l[r] * alpha[r] + sm[r];
#pragma unroll
      for (int n = 0; n < 8; ++n)
#pragma unroll
        for (int r = 0; r < 4; ++r) o[n][r] *= alpha[r];

      // ---- P (score layout) -> per-wave LDS (swizzled) -> A-operand fragments ----
#pragma unroll
      for (int n = 0; n < 4; ++n)
#pragma unroll
        for (int r = 0; r < 4; ++r) {
          int row = lgrp * 4 + r;
          int byte = row * 128 + (n * 16 + lrow) * 2;
          byte ^= (row & 7) << 4;
          *reinterpret_cast<unsigned short*>(reinterpret_cast<char*>(pb) + byte) = f2b(p[n][r]);
        }
      asm volatile("s_waitcnt lgkmcnt(0)" ::: "memory");
      __builtin_amdgcn_sched_barrier(0);
      int rbyte0 = (lrow * 128 + lgrp * 16) ^ ((lrow & 7) << 4);
      int rbyte1 = (lrow * 128 + 64 + lgrp * 16) ^ ((lrow & 7) << 4);
      short8 pf0 = *reinterpret_cast<const short8*>(reinterpret_cast<char*>(pb) + rbyte0);
      short8 pf1 = *reinterpret_cast<const short8*>(reinterpret_cast<char*>(pb) + rbyte1);

      // ---- PV: O += P @ V from LDS ----
      const char* vbp = vbuf[cur];
#pragma unroll
      for (int n = 0; n < 8; ++n) {
        int u0 = (n * 16 + lrow) * 128 + lgrp * 16;
        short8 vf0 = *reinterpret_cast<const short8*>(vbp + (u0 ^ ((lrow & 7) << 4)));
        short8 vf1 = *reinterpret_cast<const short8*>(vbp + ((u0 + 64) ^ ((lrow & 7) << 4)));
        o[n] = __builtin_amdgcn_mfma_f32_16x16x32_bf16(pf0, vf0, o[n], 0, 0, 0);
        o[n] = __builtin_amdgcn_mfma_f32_16x16x32_bf16(pf1, vf1, o[n], 0, 0, 0);
      }
    }
    __syncthreads();   // next buf ready + all waves done reading cur
  }

  // ---- store partial (unnormalized O bf16, running m/l f32); slot == blockIdx.x ----
  unsigned short* po = pO + (size_t)bx * (64 * 128) + (size_t)(16 * w) * 128;
#pragma unroll
  for (int n = 0; n < 8; ++n)
#pragma unroll
    for (int r = 0; r < 4; ++r)
      po[(size_t)(lgrp * 4 + r) * 128 + n * 16 + lrow] = f2b(o[n][r]);
  if (lrow == 0) {
#pragma unroll
    for (int r = 0; r < 4; ++r) {
      pm[(size_t)bx * 64 + 16 * w + lgrp * 4 + r] = m[r];
      pl[(size_t)bx * 64 + 16 * w + lgrp * 4 + r] = l[r];
    }
  }
}

// ------------- combine split-KV partials: 256 blocks, each 64 rows x 128 cols -------------
__global__ __launch_bounds__(256) void combine_kernel(const unsigned short* __restrict__ pO,
                                                      const float* __restrict__ pm,
                                                      const float* __restrict__ pl,
                                                      float* __restrict__ out) {
  const int tile = blockIdx.x;      // 0..255: (b, g)
  const int b = tile >> 5;
  const int g = tile & 31;
  const int qq = g >> 2, rr = g & 3;
  const int nseg = qq + 1;
  const int slot0 = b * BLOCKS_PER_B + g + 2 * qq * (qq - 1) + qq * rr;

  __shared__ float fac[8][64];
  const int t = threadIdx.x;
  if (t < 64) {
    float M = -1e30f;
    for (int s = 0; s < nseg; ++s) M = fmaxf(M, pm[(size_t)(slot0 + s) * 64 + t]);
    float L = 0.f;
    for (int s = 0; s < nseg; ++s)
      L += pl[(size_t)(slot0 + s) * 64 + t] * exp2f(pm[(size_t)(slot0 + s) * 64 + t] - M);
    float inv = 1.0f / L;
    for (int s = 0; s < nseg; ++s)
      fac[s][t] = exp2f(pm[(size_t)(slot0 + s) * 64 + t] - M) * inv;
  }
  __syncthreads();

#pragma unroll
  for (int pass = 0; pass < 8; ++pass) {
    int i4 = pass * 256 + t;        // 0..2047 float4s (64 rows x 32 float4/row)
    int row = i4 >> 5;
    int c4 = i4 & 31;
    float4 acc = make_float4(0.f, 0.f, 0.f, 0.f);
    for (int s = 0; s < nseg; ++s) {
      const ushort4 u = reinterpret_cast<const ushort4*>(pO + (size_t)(slot0 + s) * 8192 + row * 128)[c4];
      float f = fac[s][row];
      acc.x += b2f(u.x) * f;
      acc.y += b2f(u.y) * f;
      acc.z += b2f(u.z) * f;
      acc.w += b2f(u.w) * f;
    }
    reinterpret_cast<float4*>(out + ((size_t)b * Tq + g * 64 + row) * Dq)[c4] = acc;
  }
}

extern "C" void kernel_launch(void* const* d_in, const int* in_sizes, int n_in,
                              void* d_out, int out_size, void* d_ws, size_t ws_size,
                              hipStream_t stream) {
  // setup_inputs order: x, Wk, Wq, Wv
  const float* x  = (const float*)d_in[0];
  const float* Wk = (const float*)d_in[1];
  const float* Wq = (const float*)d_in[2];
  const float* Wv = (const float*)d_in[3];
  float* out = (float*)d_out;

  // workspace (bf16 elems): wt[3][D][E] | q | k | vT | pO | pm | pl  (~46 MB)
  unsigned short* wt = (unsigned short*)d_ws;
  unsigned short* qb = wt + (size_t)3 * Dq * Eq;
  unsigned short* kb = qb + (size_t)Bq * Tq * Dq;
  unsigned short* vb = kb + (size_t)Bq * Tq * Dq;
  unsigned short* pO = vb + (size_t)Bq * Tq * Dq;
  float* pm = (float*)(pO + (size_t)NBLK * 64 * 128);
  float* pl = pm + (size_t)NBLK * 64;

  prep_w_kernel<<<48, 256, 0, stream>>>(Wq, Wk, Wv, wt);
  proj3_kernel<<<Bq * Tq / 64, 512, 0, stream>>>(x, wt, qb, kb, vb);
  attn_kernel<<<NBLK, 256, 0, stream>>>(qb, kb, vb, pO, pm, pl);
  combine_kernel<<<Bq * Tq / 64, 256, 0, stream>>>(pO, pm, pl, out);
}

// Round 7
// 102.679 us; speedup vs baseline: 1.0969x; 1.0969x over previous
//
#include <hip/hip_runtime.h>
#include <hip/hip_bf16.h>
#include <stdint.h>

// Problem constants (SelfAttentionHead): B=8, T=2048, E=1024, D=128
#define Bq 8
#define Tq 2048
#define Eq 1024
#define Dq 128
#define BLOCKS_PER_B 144          // sum_{g=0..31} ceil((g+1)/4), LSEG=256
#define NBLK (Bq * BLOCKS_PER_B)  // 1152

typedef __attribute__((ext_vector_type(8))) short short8;   // 8 x bf16 (4 VGPR) MFMA frag
typedef __attribute__((ext_vector_type(4))) float f32x4;    // MFMA accumulator

__device__ __forceinline__ unsigned short f2b(float f) {
  __hip_bfloat16 h = __float2bfloat16(f);   // RNE
  return __builtin_bit_cast(unsigned short, h);
}
__device__ __forceinline__ float b2f(unsigned short u) {
  unsigned int x = ((unsigned int)u) << 16;
  return __builtin_bit_cast(float, x);
}
__device__ __forceinline__ void gload16(const void* g, void* l) {
  __builtin_amdgcn_global_load_lds(
      (const __attribute__((address_space(1))) unsigned int*)g,
      (__attribute__((address_space(3))) unsigned int*)l, 16, 0, 0);
}

// ------------- weights: transpose + cast via LDS -> wt[p][d][e] = W_p[e][d]; p: 0=Wq 1=Wk 2=Wv -------------
__global__ __launch_bounds__(256) void prep_w_kernel(const float* __restrict__ wq,
                                                     const float* __restrict__ wk,
                                                     const float* __restrict__ wv,
                                                     unsigned short* __restrict__ wt) {
  __shared__ float tile[64][129];
  const int p  = blockIdx.x >> 4;
  const int e0 = (blockIdx.x & 15) * 64;
  const float* w = (p == 0) ? wq : (p == 1) ? wk : wv;
  const int tid = threadIdx.x;
#pragma unroll
  for (int i = 0; i < 32; ++i) {
    int idx = i * 256 + tid;            // 0..8191
    int r = idx >> 7, c = idx & 127;
    tile[r][c] = w[(size_t)(e0 + r) * Dq + c];
  }
  __syncthreads();
  const int d = tid >> 1;
  const int es = (tid & 1) * 32;
  unsigned short* dst = wt + (size_t)p * Dq * Eq + (size_t)d * Eq + e0 + es;
#pragma unroll
  for (int c4 = 0; c4 < 8; ++c4) {
    ushort4 u;
    u.x = f2b(tile[es + c4 * 4 + 0][d]);
    u.y = f2b(tile[es + c4 * 4 + 1][d]);
    u.z = f2b(tile[es + c4 * 4 + 2][d]);
    u.w = f2b(tile[es + c4 * 4 + 3][d]);
    *reinterpret_cast<ushort4*>(dst + c4 * 4) = u;
  }
}

// ------------- fused projection GEMM: C[16384 x 384] = x(f32) @ [Wq|Wk|Wv] -------------
// 256 blocks x 512 thr (8 waves; wave = 64 rows x 48 cols = 4x3 frags). BK=32, 32 steps.
// B: DIRECT global->reg, 1-step prefetch (wt is L2-resident; loads span barriers freely).
// A: reg-staged f32->bf16 into [kchunk][row] LDS ping-pong, written late (2-step-lookahead x load).
// Per-step sync: lgkmcnt(0) + raw s_barrier ONLY — no vmcnt drain in the loop.
__global__ __launch_bounds__(512, 2) void proj3_kernel(const float* __restrict__ x,
                                                       const unsigned short* __restrict__ wt,
                                                       unsigned short* __restrict__ qo,
                                                       unsigned short* __restrict__ ko,
                                                       unsigned short* __restrict__ vo) {
  __shared__ __align__(16) char As[2][4096];    // 4 kchunks x 64 rows x 16B (8 bf16)

  const int row0 = blockIdx.x * 64;
  const int tid  = threadIdx.x;
  const int lane = tid & 63;
  const int w    = tid >> 6;                    // 0..7; wave cols [48w, 48w+48)
  const int lrow = lane & 15;
  const int lgrp = lane >> 4;

  // A staging: thread -> (row = tid>>3, 4-float chunk h = tid&7)
  const int arow = tid >> 3;
  const int h    = tid & 7;
  const float* xsrc = x + (size_t)(row0 + arow) * Eq + h * 4;
  const int awoff = (h >> 1) * 1024 + arow * 16 + (h & 1) * 8;
  // A frag read offset (lane): kchunk=lgrp, row=16m+lrow
  const int aroff = lgrp * 1024 + lrow * 16;

  // B frag pointers (lane-private cols, 2KB stride; 16B per lane-group chunk)
  const char* wtb = (const char*)wt;
  const char* bp0 = wtb + (size_t)(w * 48 +  0 + lrow) * 2048 + lgrp * 16;
  const char* bp1 = wtb + (size_t)(w * 48 + 16 + lrow) * 2048 + lgrp * 16;
  const char* bp2 = wtb + (size_t)(w * 48 + 32 + lrow) * 2048 + lgrp * 16;

  f32x4 acc[4][3];
#pragma unroll
  for (int m = 0; m < 4; ++m)
#pragma unroll
    for (int n = 0; n < 3; ++n) acc[m][n] = (f32x4){0.f, 0.f, 0.f, 0.f};

  short8 B0[3], B1[3];
  float4 Xa, Xb;

  // ---- prologue: A(0) staged; x(1) and B(0) in flight ----
  Xb = *reinterpret_cast<const float4*>(xsrc);            // x(0)
  B0[0] = *reinterpret_cast<const short8*>(bp0);          // B(0)
  B0[1] = *reinterpret_cast<const short8*>(bp1);
  B0[2] = *reinterpret_cast<const short8*>(bp2);
  Xa = *reinterpret_cast<const float4*>(xsrc + 32);       // x(1)
  {
    ushort4 u;
    u.x = f2b(Xb.x); u.y = f2b(Xb.y); u.z = f2b(Xb.z); u.w = f2b(Xb.w);
    *reinterpret_cast<ushort4*>(As[0] + awoff) = u;
  }
  asm volatile("s_waitcnt lgkmcnt(0)" ::: "memory");
  __builtin_amdgcn_s_barrier();

  // one K-step: compute from As[t&1] with BU; prefetch x(t+2)->XL, B(t+1)->BL; write A(t+1)
  auto STEP = [&](int t, float4& XW, float4& XL, short8 (&BU)[3], short8 (&BL)[3],
                  bool loadX, bool loadB, bool writeA) {
    if (loadX) XL = *reinterpret_cast<const float4*>(xsrc + (t + 2) * 32);
    if (loadB) {
      BL[0] = *reinterpret_cast<const short8*>(bp0 + (t + 1) * 64);
      BL[1] = *reinterpret_cast<const short8*>(bp1 + (t + 1) * 64);
      BL[2] = *reinterpret_cast<const short8*>(bp2 + (t + 1) * 64);
    }
    const char* Ab = As[t & 1];
    short8 af[4];
#pragma unroll
    for (int m = 0; m < 4; ++m)
      af[m] = *reinterpret_cast<const short8*>(Ab + aroff + m * 256);
#pragma unroll
    for (int m = 0; m < 4; ++m)
#pragma unroll
      for (int n = 0; n < 3; ++n)
        acc[m][n] = __builtin_amdgcn_mfma_f32_16x16x32_bf16(af[m], BU[n], acc[m][n], 0, 0, 0);
    if (writeA) {
      ushort4 u;
      u.x = f2b(XW.x); u.y = f2b(XW.y); u.z = f2b(XW.z); u.w = f2b(XW.w);
      *reinterpret_cast<ushort4*>(As[(t + 1) & 1] + awoff) = u;
    }
    asm volatile("s_waitcnt lgkmcnt(0)" ::: "memory");
    __builtin_amdgcn_sched_barrier(0);
    __builtin_amdgcn_s_barrier();
  };

  for (int tt = 0; tt < 30; tt += 2) {
    STEP(tt,     Xa, Xb, B0, B1, true,  true,  true);
    STEP(tt + 1, Xb, Xa, B1, B0, true,  true,  true);
  }
  STEP(30, Xa, Xb, B0, B1, false, true,  true);   // B(31) -> B1; A(31) written
  STEP(31, Xb, Xa, B1, B0, false, false, false);  // final compute

  // ---- epilogue: C/D layout col=lane&15, row=(lane>>4)*4+reg ----
  const int rg   = lgrp * 4;
  const int lcol = lrow;
#pragma unroll
  for (int m = 0; m < 4; ++m)
#pragma unroll
    for (int n = 0; n < 3; ++n) {
      int col = w * 48 + n * 16 + lcol;
      int p = col >> 7, d = col & 127;
#pragma unroll
      for (int r = 0; r < 4; ++r) {
        int row = row0 + m * 16 + rg + r;
        float v = acc[m][n][r];
        if (p == 0)      qo[(size_t)row * Dq + d] = f2b(v);
        else if (p == 1) ko[(size_t)row * Dq + d] = f2b(v);
        else             vo[(size_t)(row >> 11) * Dq * Tq + (size_t)d * Tq + (row & (Tq - 1))] = f2b(v);
      }
    }
}

// ------------- split-KV causal flash attention, block-cooperative LDS staging -------------
// Block (256 thr = 4 waves) = (batch b, 64-row Q group g, KV segment s of 256).
// Counted-vmcnt pipeline (T4): per step, next tile's 8 gload_lds stay in flight across
// the barriers; only the previous tile's loads are waited (vmcnt(8)). Two raw s_barriers
// per step (pre-compute: cur ready; post-compute: cur free for overwrite).
__global__ __launch_bounds__(256) void attn_kernel(const unsigned short* __restrict__ q,
                                                   const unsigned short* __restrict__ k,
                                                   const unsigned short* __restrict__ vT,
                                                   unsigned short* __restrict__ pO,
                                                   float* __restrict__ pm,
                                                   float* __restrict__ pl) {
  __shared__ __align__(16) char kbuf[2][16384];            // K tile: 64 rows x 256B
  __shared__ __align__(16) char vbuf[2][16384];            // V tile: 128 d-rows x 128B
  __shared__ __align__(16) unsigned short pbuf[4][1024];   // per-wave P tile 16x64

  const int lane = threadIdx.x & 63;
  const int w    = threadIdx.x >> 6;
  const int bx   = blockIdx.x;
  const int b    = bx / BLOCKS_PER_B;
  int rm = bx - b * BLOCKS_PER_B;
  int g = 0, s = 0;
#pragma unroll
  for (int c = 1; c <= 8; ++c) {        // groups 4(c-1)..4c-1 have c segments each
    int cnt = 4 * c;
    if (rm < cnt) { g = 4 * (c - 1) + rm / c; s = rm % c; break; }
    rm -= cnt;
  }
  const int kv0      = 256 * s;
  const int kend_blk = min(kv0 + 256, 64 * g + 64);
  const int qb0      = 64 * g + 16 * w;
  const int kend_w   = qb0 + 16;

  const int lrow = lane & 15;
  const int lgrp = lane >> 4;
  const int lk8  = lgrp * 8;
  const float kscale = 0.08838834764831845f * 1.44269504088896340736f; // D^-0.5 * log2(e)
  unsigned short* pb = pbuf[w];
  const char* kgbase = (const char*)(k + (size_t)b * Tq * Dq);
  const char* vgbase = (const char*)(vT + (size_t)b * Dq * Tq);

  // cooperative stage of one 64-col K/V tile pair into buffer `bufi` (8 gload16 per wave)
  auto STAGE = [&](int bufi, int kvb) {
    const char* ksrc = kgbase + (size_t)kvb * 256;   // contiguous 16KB
    char* kl = kbuf[bufi];
    char* vl = vbuf[bufi];
    const int kvb2 = kvb * 2;
#pragma unroll
    for (int i = 0; i < 4; ++i) {
      int y  = i * 4096 + w * 1024;                  // wave-uniform LDS byte base
      int yl = y + lane * 16;                        // this lane's dest byte
      int src = yl ^ ((((yl >> 8) & 7)) << 4);       // inverse swizzle on source
      gload16(ksrc + src, kl + y);
    }
#pragma unroll
    for (int i = 0; i < 4; ++i) {
      int y  = i * 4096 + w * 1024;
      int yl = y + lane * 16;
      int d  = yl >> 7;
      int src = d * 4096 + kvb2 + ((yl & 127) ^ ((d & 7) << 4));
      gload16(vgbase + src, vl + y);
    }
  };

  // Q fragments (registers)
  short8 qf[4];
  const unsigned short* qrow = q + ((size_t)b * Tq + qb0 + lrow) * Dq;
#pragma unroll
  for (int kc = 0; kc < 4; ++kc)
    qf[kc] = *reinterpret_cast<const short8*>(qrow + kc * 32 + lk8);

  f32x4 o[8];
#pragma unroll
  for (int n = 0; n < 8; ++n) o[n] = (f32x4){0.f, 0.f, 0.f, 0.f};
  float m[4], l[4];
#pragma unroll
  for (int r = 0; r < 4; ++r) { m[r] = -1e30f; l[r] = 0.f; }
  const int rowg = qb0 + lgrp * 4;

  STAGE(0, kv0);
  const int nsteps = (kend_blk - kv0) >> 6;

  for (int t = 0; t < nsteps; ++t) {
    const int kvb = kv0 + (t << 6);
    const int cur = t & 1;
    if (t + 1 < nsteps) {
      STAGE(cur ^ 1, kvb + 64);                      // 8 loads stay in flight across barriers
      asm volatile("s_waitcnt vmcnt(8)" ::: "memory");   // wait only tile t's 8
    } else {
      asm volatile("s_waitcnt vmcnt(0)" ::: "memory");
    }
    __builtin_amdgcn_sched_barrier(0);
    __builtin_amdgcn_s_barrier();                    // cur ready for all waves

    if (kvb < kend_w) {
      const char* kbp = kbuf[cur];
      // ---- QK^T: 64 score cols from LDS ----
      f32x4 sf[4];
#pragma unroll
      for (int n = 0; n < 4; ++n) sf[n] = (f32x4){0.f, 0.f, 0.f, 0.f};
#pragma unroll
      for (int kc = 0; kc < 4; ++kc)
#pragma unroll
        for (int n = 0; n < 4; ++n) {
          int u = (n * 16 + lrow) * 256 + kc * 64 + lgrp * 16;
          short8 kf = *reinterpret_cast<const short8*>(kbp + (u ^ ((lrow & 7) << 4)));
          sf[n] = __builtin_amdgcn_mfma_f32_16x16x32_bf16(qf[kc], kf, sf[n], 0, 0, 0);
        }

      // ---- scale + causal mask + online softmax ----
      const bool needmask = (kvb + 64 > qb0);
      float p[4][4], mx[4];
#pragma unroll
      for (int r = 0; r < 4; ++r) mx[r] = -1e30f;
#pragma unroll
      for (int n = 0; n < 4; ++n)
#pragma unroll
        for (int r = 0; r < 4; ++r) {
          float aa = sf[n][r] * kscale;
          if (needmask && (kvb + n * 16 + lrow > rowg + r)) aa = -1e30f;
          p[n][r] = aa;
          mx[r] = fmaxf(mx[r], aa);
        }
#pragma unroll
      for (int off = 1; off < 16; off <<= 1)
#pragma unroll
        for (int r = 0; r < 4; ++r) mx[r] = fmaxf(mx[r], __shfl_xor(mx[r], off, 64));

      float alpha[4], sm[4];
#pragma unroll
      for (int r = 0; r < 4; ++r) {
        float mn = fmaxf(m[r], mx[r]);
        alpha[r] = exp2f(m[r] - mn);
        m[r] = mn;
        sm[r] = 0.f;
#pragma unroll
        for (int n = 0; n < 4; ++n) {
          p[n][r] = exp2f(p[n][r] - mn);
          sm[r] += p[n][r];
        }
      }
#pragma unroll
      for (int off = 1; off < 16; off <<= 1)
#pragma unroll
        for (int r = 0; r < 4; ++r) sm[r] += __shfl_xor(sm[r], off, 64);
#pragma unroll
      for (int r = 0; r < 4; ++r) l[r] = l[r] * alpha[r] + sm[r];
#pragma unroll
      for (int n = 0; n < 8; ++n)
#pragma unroll
        for (int r = 0; r < 4; ++r) o[n][r] *= alpha[r];

      // ---- P (score layout) -> per-wave LDS (swizzled) -> A-operand fragments ----
#pragma unroll
      for (int n = 0; n < 4; ++n)
#pragma unroll
        for (int r = 0; r < 4; ++r) {
          int row = lgrp * 4 + r;
          int byte = row * 128 + (n * 16 + lrow) * 2;
          byte ^= (row & 7) << 4;
          *reinterpret_cast<unsigned short*>(reinterpret_cast<char*>(pb) + byte) = f2b(p[n][r]);
        }
      asm volatile("s_waitcnt lgkmcnt(0)" ::: "memory");
      __builtin_amdgcn_sched_barrier(0);
      int rbyte0 = (lrow * 128 + lgrp * 16) ^ ((lrow & 7) << 4);
      int rbyte1 = (lrow * 128 + 64 + lgrp * 16) ^ ((lrow & 7) << 4);
      short8 pf0 = *reinterpret_cast<const short8*>(reinterpret_cast<char*>(pb) + rbyte0);
      short8 pf1 = *reinterpret_cast<const short8*>(reinterpret_cast<char*>(pb) + rbyte1);

      // ---- PV: O += P @ V from LDS ----
      const char* vbp = vbuf[cur];
#pragma unroll
      for (int n = 0; n < 8; ++n) {
        int u0 = (n * 16 + lrow) * 128 + lgrp * 16;
        short8 vf0 = *reinterpret_cast<const short8*>(vbp + (u0 ^ ((lrow & 7) << 4)));
        short8 vf1 = *reinterpret_cast<const short8*>(vbp + ((u0 + 64) ^ ((lrow & 7) << 4)));
        o[n] = __builtin_amdgcn_mfma_f32_16x16x32_bf16(pf0, vf0, o[n], 0, 0, 0);
        o[n] = __builtin_amdgcn_mfma_f32_16x16x32_bf16(pf1, vf1, o[n], 0, 0, 0);
      }
    }
    __builtin_amdgcn_s_barrier();   // all waves done reading cur; safe to overwrite next iter
  }

  // ---- store partial (unnormalized O bf16, running m/l f32); slot == blockIdx.x ----
  unsigned short* po = pO + (size_t)bx * (64 * 128) + (size_t)(16 * w) * 128;
#pragma unroll
  for (int n = 0; n < 8; ++n)
#pragma unroll
    for (int r = 0; r < 4; ++r)
      po[(size_t)(lgrp * 4 + r) * 128 + n * 16 + lrow] = f2b(o[n][r]);
  if (lrow == 0) {
#pragma unroll
    for (int r = 0; r < 4; ++r) {
      pm[(size_t)bx * 64 + 16 * w + lgrp * 4 + r] = m[r];
      pl[(size_t)bx * 64 + 16 * w + lgrp * 4 + r] = l[r];
    }
  }
}

// ------------- combine split-KV partials: 256 blocks, each 64 rows x 128 cols -------------
__global__ __launch_bounds__(256) void combine_kernel(const unsigned short* __restrict__ pO,
                                                      const float* __restrict__ pm,
                                                      const float* __restrict__ pl,
                                                      float* __restrict__ out) {
  const int tile = blockIdx.x;      // 0..255: (b, g)
  const int b = tile >> 5;
  const int g = tile & 31;
  const int qq = g >> 2, rr = g & 3;
  const int nseg = qq + 1;
  const int slot0 = b * BLOCKS_PER_B + g + 2 * qq * (qq - 1) + qq * rr;

  __shared__ float fac[8][64];
  const int t = threadIdx.x;
  if (t < 64) {
    float M = -1e30f;
    for (int s = 0; s < nseg; ++s) M = fmaxf(M, pm[(size_t)(slot0 + s) * 64 + t]);
    float L = 0.f;
    for (int s = 0; s < nseg; ++s)
      L += pl[(size_t)(slot0 + s) * 64 + t] * exp2f(pm[(size_t)(slot0 + s) * 64 + t] - M);
    float inv = 1.0f / L;
    for (int s = 0; s < nseg; ++s)
      fac[s][t] = exp2f(pm[(size_t)(slot0 + s) * 64 + t] - M) * inv;
  }
  __syncthreads();

#pragma unroll
  for (int pass = 0; pass < 8; ++pass) {
    int i4 = pass * 256 + t;        // 0..2047 float4s (64 rows x 32 float4/row)
    int row = i4 >> 5;
    int c4 = i4 & 31;
    float4 acc = make_float4(0.f, 0.f, 0.f, 0.f);
    for (int s = 0; s < nseg; ++s) {
      const ushort4 u = reinterpret_cast<const ushort4*>(pO + (size_t)(slot0 + s) * 8192 + row * 128)[c4];
      float f = fac[s][row];
      acc.x += b2f(u.x) * f;
      acc.y += b2f(u.y) * f;
      acc.z += b2f(u.z) * f;
      acc.w += b2f(u.w) * f;
    }
    reinterpret_cast<float4*>(out + ((size_t)b * Tq + g * 64 + row) * Dq)[c4] = acc;
  }
}

extern "C" void kernel_launch(void* const* d_in, const int* in_sizes, int n_in,
                              void* d_out, int out_size, void* d_ws, size_t ws_size,
                              hipStream_t stream) {
  // setup_inputs order: x, Wk, Wq, Wv
  const float* x  = (const float*)d_in[0];
  const float* Wk = (const float*)d_in[1];
  const float* Wq = (const float*)d_in[2];
  const float* Wv = (const float*)d_in[3];
  float* out = (float*)d_out;

  // workspace (bf16 elems): wt[3][D][E] | q | k | vT | pO | pm | pl  (~46 MB)
  unsigned short* wt = (unsigned short*)d_ws;
  unsigned short* qb = wt + (size_t)3 * Dq * Eq;
  unsigned short* kb = qb + (size_t)Bq * Tq * Dq;
  unsigned short* vb = kb + (size_t)Bq * Tq * Dq;
  unsigned short* pO = vb + (size_t)Bq * Tq * Dq;
  float* pm = (float*)(pO + (size_t)NBLK * 64 * 128);
  float* pl = pm + (size_t)NBLK * 64;

  prep_w_kernel<<<48, 256, 0, stream>>>(Wq, Wk, Wv, wt);
  proj3_kernel<<<Bq * Tq / 64, 512, 0, stream>>>(x, wt, qb, kb, vb);
  attn_kernel<<<NBLK, 256, 0, stream>>>(qb, kb, vb, pO, pm, pl);
  combine_kernel<<<Bq * Tq / 64, 256, 0, stream>>>(pO, pm, pl, out);
}